// Round 10
// baseline (526.945 us; speedup 1.0000x reference)
//
#include <hip/hip_runtime.h>
#include <math.h>

// ---- problem constants ----
#define TB        256           // threads per block = 4 waves
#define POSB      64            // positions per block (1 per lane, shared by all waves)
#define GROUPS    4             // K-split: wave g scans codes [g*KPG,(g+1)*KPG)
#define KPG       128           // codes per group
#define KB        2             // codes per pass
#define NPOS      131072        // B*H*W positions
#define KCODES    512
#define DIM       64
#define HW        4096          // H*W
#define STRIDE    65            // dwords per LDS x2 row: odd -> bank=(l+d)%32, conflict-free
#define LOSS_OFF  8388608ull
#define ENC_OFF   8388609ull    // encodings: 67108864 dwords
#define PERP_OFF  75497473ull

__device__ __forceinline__ float tree8(float r0, float r1, float r2, float r3,
                                       float r4, float r5, float r6, float r7) {
    // numpy pairwise combine: ((r0+r1)+(r2+r3)) + ((r4+r5)+(r6+r7))
    return __fadd_rn(__fadd_rn(__fadd_rn(r0, r1), __fadd_rn(r2, r3)),
                     __fadd_rn(__fadd_rn(r4, r5), __fadd_rn(r6, r7)));
}

// Prep: ww[k] = sum(w[k]^2) in numpy pairwise order; zero counts + loss accumulator.
extern "C" __global__ __launch_bounds__(512)
void vq_prep(const float* __restrict__ w, float* __restrict__ ww,
             int* __restrict__ counts, float* __restrict__ lossAcc)
{
    const int k = threadIdx.x;                 // 512 threads
    const float* wk = w + k * DIM;
    float r[8];
    #pragma unroll
    for (int i = 0; i < 8; ++i) {
        #pragma unroll
        for (int j = 0; j < 8; ++j) {
            float v = wk[i * 8 + j];
            float pp = __fmul_rn(v, v);
            r[j] = (i == 0) ? pp : __fadd_rn(r[j], pp);
        }
    }
    ww[k] = tree8(r[0], r[1], r[2], r[3], r[4], r[5], r[6], r[7]);
    counts[k] = 0;
    if (k == 0) *lossAcc = 0.0f;
}

// Main kernel, R10: DESIGN FOR 56 VGPRs (stop fighting the allocator — at
// TB=256 it pins ~56-60 regardless of launch_bounds/waves_per_eu/LDS, proven
// R1/R2/R7/R8/R9). x2 lives in ONE shared LDS copy (64 rows x 65 dwords;
// odd stride -> ds_read_b32 bank=(l+d)%32, 2-way only = free). 4-wave K-split
// reuses the same rows -> LDS ~20.5KB -> 7 blocks/CU -> 28 waves/CU hides the
// wave-uniform s_load w-stream. KB=2 keeps live regs ~40. Encodings zero-fill
// fused back in (R4-proven coalesced float4 pattern) to overlap ~45us of
// fill HBM time with compute.
extern "C" __global__ __launch_bounds__(TB)
void vq_scan(const float* __restrict__ x, const float* __restrict__ w,
             const float* __restrict__ ww, float* __restrict__ out,
             int* __restrict__ counts, float* __restrict__ lossAcc)
{
    __shared__ float x2ls[POSB * STRIDE];      // 16640 B, 2x values
    __shared__ float cdist[GROUPS][POSB];      // 1024 B
    __shared__ int   ckidx[GROUPS][POSB];      // 1024 B
    __shared__ int   hcount[KCODES];           // 2048 B

    const int tid = threadIdx.x;
    const int l   = tid & 63;                                  // lane = position slot
    const int g   = __builtin_amdgcn_readfirstlane(tid >> 6);  // wave id, uniform
    const int n   = blockIdx.x * POSB + l;                     // position (64|4096: one b per block)
    const int b   = n >> 12;
    const int hw  = n & 4095;

    hcount[tid]      = 0;
    hcount[tid + TB] = 0;

    // ---- prologue: wave g loads dims [16g,16g+16) of its lane's position
    // (coalesced) and stores 2x into the shared row. One x2 copy per block.
    const float* xp = x + ((size_t)b * DIM) * HW + hw;
    float* row = &x2ls[l * STRIDE];
    #pragma unroll
    for (int t = 0; t < 16; ++t) {
        const int d = 16 * g + t;              // g uniform
        float v = xp[(size_t)d * HW];
        row[d] = v + v;                        // exact doubling
    }
    __syncthreads();                           // full x2 rows + hcount visible

    // ---- A = sum(x^2) from LDS, replicating numpy pairwise_sum(64):
    // r[j] over i ascending; xe = 0.5f*(2x) is bit-exact x.
    float r[8];
    #pragma unroll
    for (int i = 0; i < 8; ++i) {
        #pragma unroll
        for (int j = 0; j < 8; ++j) {
            float xe = 0.5f * row[i * 8 + j];
            float pp = __fmul_rn(xe, xe);
            r[j] = (i == 0) ? pp : __fadd_rn(r[j], pp);
        }
    }
    const float A = tree8(r[0], r[1], r[2], r[3], r[4], r[5], r[6], r[7]);

    // ---- scan my 128-code group, 2 codes per pass; fused coalesced zero-fill.
    // Tile = POSB*KCODES = 32768 dwords at T0 (T0%4==1): dwords 3+4m aligned;
    // m=8191 would cross the tile edge -> written as edge dword below.
    float best  = INFINITY;
    int   bestk = 0;
    const size_t T0 = ENC_OFF + (size_t)blockIdx.x * (POSB * KCODES);
    float4* zs4 = reinterpret_cast<float4*>(out + T0 + 3);
    const float4 zero4 = make_float4(0.0f, 0.0f, 0.0f, 0.0f);

    for (int p = 0; p < KPG / KB; ++p) {       // 64 passes
        const int k0 = g * KPG + p * KB;       // wave-uniform -> s_load path
        const float* w0 = w + (size_t)k0 * DIM;
        float s0[8], s1[8];
        #pragma unroll
        for (int c = 0; c < 16; ++c) {
            const int j = (c & 1) * 4;
            // 4 conflict-free ds_read_b32 from own row, reused by 2 codes
            float xa = row[4 * c + 0];
            float xb = row[4 * c + 1];
            float xc = row[4 * c + 2];
            float xd = row[4 * c + 3];
            const float* wc0 = w0 + 4 * c;
            const float* wc1 = w0 + DIM + 4 * c;
            if (c < 2) {
                s0[j]   = __fmul_rn(xa, wc0[0]);  s1[j]   = __fmul_rn(xa, wc1[0]);
                s0[j+1] = __fmul_rn(xb, wc0[1]);  s1[j+1] = __fmul_rn(xb, wc1[1]);
                s0[j+2] = __fmul_rn(xc, wc0[2]);  s1[j+2] = __fmul_rn(xc, wc1[2]);
                s0[j+3] = __fmul_rn(xd, wc0[3]);  s1[j+3] = __fmul_rn(xd, wc1[3]);
            } else {
                s0[j]   = __fmaf_rn(xa, wc0[0], s0[j]);    s1[j]   = __fmaf_rn(xa, wc1[0], s1[j]);
                s0[j+1] = __fmaf_rn(xb, wc0[1], s0[j+1]);  s1[j+1] = __fmaf_rn(xb, wc1[1], s1[j+1]);
                s0[j+2] = __fmaf_rn(xc, wc0[2], s0[j+2]);  s1[j+2] = __fmaf_rn(xc, wc1[2], s1[j+2]);
                s0[j+3] = __fmaf_rn(xd, wc0[3], s0[j+3]);  s1[j+3] = __fmaf_rn(xd, wc1[3], s1[j+3]);
            }
        }
        float dot0  = tree8(s0[0], s0[1], s0[2], s0[3], s0[4], s0[5], s0[6], s0[7]);
        float dot1  = tree8(s1[0], s1[1], s1[2], s1[3], s1[4], s1[5], s1[6], s1[7]);
        float dist0 = __fadd_rn(__fadd_rn(A, ww[k0]),     -dot0);
        float dist1 = __fadd_rn(__fadd_rn(A, ww[k0 + 1]), -dot1);
        if (dist0 < best) { best = dist0; bestk = k0; }        // ascending k:
        if (dist1 < best) { best = dist1; bestk = k0 + 1; }    // ties keep first

        if (p < 32) {                          // 8191 float4 / 256 thr = 32/thr
            const int m = p * TB + tid;        // [0, 8192)
            if (m < 8191) zs4[m] = zero4;      // coalesced; drains behind FMAs
        }
    }
    cdist[g][l] = best;
    ckidx[g][l] = bestk;

    // edge dwords of the tile (not covered by the float4 sweep)
    if (tid < 3)  out[T0 + tid]   = 0.0f;      // d = 0,1,2
    if (tid == 3) out[T0 + 32767] = 0.0f;      // d = 32767

    __syncthreads();   // zero stores drained (vmcnt(0) at barrier); candidates visible

    // ---- merge 4 candidates (ascending g = ascending k: ties keep first) ----
    float fb = cdist[0][l];
    int   fk = ckidx[0][l];
    #pragma unroll
    for (int gg = 1; gg < GROUPS; ++gg) {
        float dg = cdist[gg][l];
        int   kg = ckidx[gg][l];
        if (dg < fb) { fb = dg; fk = kg; }
    }

    // ---- epilogue: wave 0 only ----
    if (g == 0) {
        out[ENC_OFF + (size_t)n * KCODES + fk] = 1.0f;   // one-hot after tile zeros
        atomicAdd(&hcount[fk], 1);

        const float4* wrow = reinterpret_cast<const float4*>(w + (size_t)fk * DIM);
        float* qo = out + ((size_t)b * DIM) * HW + hw;
        float sse = 0.0f;
        #pragma unroll
        for (int c = 0; c < 16; ++c) {
            float4 q = wrow[c];
            qo[(size_t)(4 * c + 0) * HW] = q.x;
            qo[(size_t)(4 * c + 1) * HW] = q.y;
            qo[(size_t)(4 * c + 2) * HW] = q.z;
            qo[(size_t)(4 * c + 3) * HW] = q.w;
            float e0 = q.x - 0.5f * row[4 * c + 0]; sse = __fmaf_rn(e0, e0, sse);
            float e1 = q.y - 0.5f * row[4 * c + 1]; sse = __fmaf_rn(e1, e1, sse);
            float e2 = q.z - 0.5f * row[4 * c + 2]; sse = __fmaf_rn(e2, e2, sse);
            float e3 = q.w - 0.5f * row[4 * c + 3]; sse = __fmaf_rn(e3, e3, sse);
        }
        // wave-level SSE reduction (64 lanes)
        #pragma unroll
        for (int off = 32; off > 0; off >>= 1) sse += __shfl_down(sse, off);
        if (l == 0) atomicAdd(lossAcc, sse);
    }

    __syncthreads();   // wave 0's hcount atomics done

    // histogram drain
    {
        int c0 = hcount[tid];       if (c0) atomicAdd(&counts[tid], c0);
        int c1 = hcount[tid + TB];  if (c1) atomicAdd(&counts[tid + TB], c1);
    }
}

// Finalize: loss scalar + perplexity from histogram.
extern "C" __global__ __launch_bounds__(512)
void vq_finalize(const int* __restrict__ counts, const float* __restrict__ lossAcc,
                 float* __restrict__ out)
{
    __shared__ double sred[KCODES];
    const int t = threadIdx.x;                 // 512 threads
    double p = (double)counts[t] * (1.0 / (double)NPOS);
    sred[t] = -p * log(p + 1e-10);
    __syncthreads();
    for (int s = KCODES / 2; s > 0; s >>= 1) {
        if (t < s) sred[t] += sred[t + s];
        __syncthreads();
    }
    if (t == 0) {
        out[PERP_OFF] = (float)exp(sred[0]);
        out[LOSS_OFF] = 1.25f * (lossAcc[0] / 8388608.0f);
    }
}

extern "C" void kernel_launch(void* const* d_in, const int* in_sizes, int n_in,
                              void* d_out, int out_size, void* d_ws, size_t ws_size,
                              hipStream_t stream)
{
    const float* x = (const float*)d_in[0];    // [32,64,64,64] fp32
    const float* w = (const float*)d_in[1];    // [512,64] fp32
    float* out = (float*)d_out;

    float* ww      = (float*)d_ws;                         // 512 floats
    int*   counts  = (int*)((char*)d_ws + 2048);           // 512 ints
    float* lossAcc = (float*)((char*)d_ws + 4096);         // 1 float

    vq_prep<<<1, 512, 0, stream>>>(w, ww, counts, lossAcc);
    vq_scan<<<NPOS / POSB, TB, 0, stream>>>(x, w, ww, out, counts, lossAcc);
    vq_finalize<<<1, 512, 0, stream>>>(counts, lossAcc, out);
}